// Round 10
// baseline (168.254 us; speedup 1.0000x reference)
//
#include <hip/hip_runtime.h>
#include <cstddef>

#define NN 3072
#define RR 16
#define FILL_BLOCKS 2048
#define FILL_ITERS 72   // NN*NN*4 quads / (FILL_BLOCKS*256) = 72 exactly

typedef float f32x4 __attribute__((ext_vector_type(4)));

// Prologue: key[i] = (cls not in {24,25,26}) ? batch[i] : -1
__global__ void frd_key_kernel(const int* __restrict__ cls,
                               const int* __restrict__ batch,
                               int* __restrict__ key) {
    int i = blockIdx.x * blockDim.x + threadIdx.x;
    if (i < NN) {
        int c = cls[i];
        bool valid = (c != 24) && (c != 25) && (c != 26);
        key[i] = valid ? batch[i] : -1;
    }
}

// Phase 1: fill entire output with the one_hot(0,R) default. Data-independent
// stores (no loads, no vmcnt stalls) -> should run at rocclr-fill speed
// (~6.7 TB/s measured on this buffer). Grid-stride, plain stores, mimicking
// __amd_rocclr_fillBufferAligned's shape.
__global__ __launch_bounds__(256)
void frd_fill_kernel(float* __restrict__ out) {
    const int t = blockIdx.x * 256 + threadIdx.x;        // [0, 524288)
    const float d0 = ((t & 3) == 0) ? 1.0f : 0.0f;       // quad q=0 gets (1,0,0,0)
    const f32x4 r = {d0, 0.0f, 0.0f, 0.0f};
    float* p = out + (size_t)t * 4;
    const size_t step = (size_t)FILL_BLOCKS * 256 * 4;   // floats per sweep
#pragma unroll 4
    for (int it = 0; it < FILL_ITERS; ++it) {
        *reinterpret_cast<f32x4*>(p) = r;
        p += step;
    }
}

// Phase 2: sparse overwrite of true pairs (~2.5% for this data distribution).
// One thread per 4 consecutive pairs of one row (NN % 4 == 0 -> same row).
// seg read is a coalesced 1 KB/wave float4 burst; true-pair writes are 64 B
// per pair, clustered along the sorted-batch diagonal blocks.
__global__ __launch_bounds__(256)
void frd_scatter_kernel(const float* __restrict__ z1,
                        const float* __restrict__ z2,
                        const float* __restrict__ seg,
                        const int* __restrict__ key,
                        float* __restrict__ out) {
    const int t = blockIdx.x * 256 + threadIdx.x;        // [0, NN*NN/4)
    const int pair0 = t * 4;
    const int i = pair0 / NN;                            // magic-mul
    const int j0 = pair0 - i * NN;

    const float4 s4 = *reinterpret_cast<const float4*>(seg + pair0);
    const int ki = key[i];                               // cache-resident
    const float sv[4] = {s4.x, s4.y, s4.z, s4.w};

#pragma unroll
    for (int c = 0; c < 4; ++c) {
        const int j = j0 + c;
        const int kj = key[j];
        // seg_eff = seg + eye; pair iff seg_eff==0, keys match, valid (ki>=0)
        const float seg_eff = sv[c] + ((i == j) ? 1.0f : 0.0f);
        const bool is_pair = (ki == kj) && (ki >= 0) && (seg_eff == 0.0f);
        if (is_pair) {
            float* op = out + (size_t)(pair0 + c) * RR;
#pragma unroll
            for (int q = 0; q < 4; ++q) {
                const float4 a = *reinterpret_cast<const float4*>(z1 + i * RR + q * 4);
                const float4 b = *reinterpret_cast<const float4*>(z2 + j * RR + q * 4);
                f32x4 r;
                r.x = a.x * b.x;
                r.y = a.y * b.y;
                r.z = a.z * b.z;
                r.w = a.w * b.w;
                __builtin_nontemporal_store(r, reinterpret_cast<f32x4*>(op + q * 4));
            }
        }
    }
}

extern "C" void kernel_launch(void* const* d_in, const int* in_sizes, int n_in,
                              void* d_out, int out_size, void* d_ws, size_t ws_size,
                              hipStream_t stream) {
    const float* z1  = (const float*)d_in[0];
    const float* z2  = (const float*)d_in[1];
    const float* seg = (const float*)d_in[2];
    const int* cls   = (const int*)d_in[3];
    const int* batch = (const int*)d_in[4];
    float* out = (float*)d_out;
    int* key = (int*)d_ws;

    frd_key_kernel<<<(NN + 255) / 256, 256, 0, stream>>>(cls, batch, key);
    frd_fill_kernel<<<FILL_BLOCKS, 256, 0, stream>>>(out);
    frd_scatter_kernel<<<NN * NN / 4 / 256, 256, 0, stream>>>(z1, z2, seg, key, out);
}